// Round 1
// baseline (408.001 us; speedup 1.0000x reference)
//
#include <hip/hip_runtime.h>
#include <cmath>

// Problem constants (match reference)
constexpr int   NCY   = 150;
constexpr int   BATCH = 65536;
constexpr float MU_MIN = 0.1f;
constexpr float MU_MAX = 1.3f;
constexpr float T_REFC = 160.0f;

// softplus(x) = logaddexp(x, 0) = max(x,0) + log1p(exp(-|x|))  (numpy's algorithm)
__device__ __forceinline__ float softplus_stable(float x) {
    return fmaxf(x, 0.0f) + log1pf(expf(-fabsf(x)));
}

__global__ __launch_bounds__(256)
void galling_sim_kernel(const float* __restrict__ params,
                        const float* __restrict__ Tptr,
                        const float* __restrict__ u,
                        const float* __restrict__ noise,
                        float* __restrict__ out)
{
    // numpy rounds every op; forbid FMA contraction so we match op-by-op fp32 rounding.
#pragma clang fp contract(off)

    const int b = blockIdx.x * blockDim.x + threadIdx.x;

    const float a0   = params[0],  a_T  = params[1],  a_mu = params[2],  a_mu2 = params[3];
    const float c0   = params[4],  c_mu = params[5],  c_T  = params[6];
    const float s0   = params[7],  s_mu = params[8],  s_T  = params[9];
    const float j0   = params[10], j_mu = params[11], j_T  = params[12];
    const float v0   = params[13], v_mu = params[14];
    const float mu0_base = params[15], mu0_T = params[16];

    const float dT = Tptr[0] - T_REFC;

    // Scalar subexpressions, evaluated in the same order numpy would (scalar ops first).
    const float A  = a0 + a_T * dT;   // (a0 + a_T*dT) — leftmost in the pi logit
    const float ct = c_T * dT;
    const float st = s_T * dT;
    const float jt = j_T * dT;

    float mu = fminf(fmaxf(mu0_base + mu0_T * dT, MU_MIN), MU_MAX);

    const float* up  = u     + b;
    const float* npp = noise + b;
    float*       o   = out   + b;
    const size_t NB  = (size_t)NCY * (size_t)BATCH;   // stride between output histories

    // 2-deep software pipeline for the streaming u/noise loads (only 1 wave/SIMD
    // at B=65536, so in-loop loads would expose ~900-cycle HBM latency).
    float u_a = up[0];
    float n_a = npp[0];
    float u_b = up[(size_t)BATCH];
    float n_b = npp[(size_t)BATCH];

    for (int t = 0; t < NCY; ++t) {
        const float u_cur = u_a;
        const float n_cur = n_a;
        u_a = u_b; n_a = n_b;
        const int tn = (t + 2 < NCY) ? (t + 2) : (NCY - 1);
        u_b = up[(size_t)tn * BATCH];
        n_b = npp[(size_t)tn * BATCH];

        // pi = sigmoid(((a0 + a_T*dT) + a_mu*mu) + (a_mu2*mu)*mu)
        const float x_pi = (A + a_mu * mu) + (a_mu2 * mu) * mu;
        const float pi   = 1.0f / (1.0f + expf(-x_pi));

        // d1 = (c0 + c_mu*mu) + c_T*dT
        const float d1 = (c0 + c_mu * mu) + ct;
        // sigma1 = softplus((s0 + s_mu*mu) + s_T*dT)
        const float sigma1 = softplus_stable((s0 + s_mu * mu) + st);
        // d2 = (j0 + j_mu*mu) + j_T*dT
        const float d2 = (j0 + j_mu * mu) + jt;
        // sigma2 = softplus(v0 + v_mu*mu)
        const float sigma2 = softplus_stable(v0 + v_mu * mu);

        const bool  is_stay   = u_cur < pi;
        const float component = is_stay ? 0.0f : 1.0f;
        const float delta_mu  = is_stay ? (d1 + sigma1 * n_cur)
                                        : (d2 + sigma2 * n_cur);
        const float mu_next   = fminf(fmaxf(mu + delta_mu, MU_MIN), MU_MAX);

        const size_t base = (size_t)t * (size_t)BATCH;
        o[0 * NB + base] = mu_next;
        o[1 * NB + base] = component;
        o[2 * NB + base] = pi;
        o[3 * NB + base] = d1;
        o[4 * NB + base] = sigma1;
        o[5 * NB + base] = d2;
        o[6 * NB + base] = sigma2;

        mu = mu_next;
    }
}

extern "C" void kernel_launch(void* const* d_in, const int* in_sizes, int n_in,
                              void* d_out, int out_size, void* d_ws, size_t ws_size,
                              hipStream_t stream) {
    const float* params = (const float*)d_in[0];
    const float* Tptr   = (const float*)d_in[1];
    const float* u      = (const float*)d_in[2];
    const float* noise  = (const float*)d_in[3];
    float*       out    = (float*)d_out;

    dim3 block(256);
    dim3 grid(BATCH / 256);   // 65536 threads, one per chain
    galling_sim_kernel<<<grid, block, 0, stream>>>(params, Tptr, u, noise, out);
}